// Round 1
// baseline (188.672 us; speedup 1.0000x reference)
//
#include <hip/hip_runtime.h>

#define NEGV -1000000000.0f

// x: [B, S, S] fp32, S = 4096. mask = (row < n-1) && (col > row) -> NEGV.
// Vectorized float4: each thread handles 4 consecutive columns of one row.
// S/4 = 1024 vecs per row -> shift 10. row index = (vec >> 10) & (S-1).
__global__ __launch_bounds__(256) void submask_kernel(
    const float4* __restrict__ x4,
    float4* __restrict__ o4,
    const int* __restrict__ n_ptr,
    int nvec)
{
    const int n = *n_ptr;                    // uniform, L2-cached
    const int nlim = n - 1;                  // rows >= nlim are untouched
    const float4 NEG4 = make_float4(NEGV, NEGV, NEGV, NEGV);

    const int stride = gridDim.x * blockDim.x;
    for (int i = blockIdx.x * blockDim.x + threadIdx.x; i < nvec; i += stride) {
        const int row = (i >> 10) & 4095;    // row within the S x S matrix
        const int c0  = (i & 1023) << 2;     // first column of this float4

        if (row >= nlim || c0 + 3 <= row) {
            // fully unmasked: plain copy
            o4[i] = x4[i];
        } else if (c0 > row) {
            // fully masked: no load needed
            o4[i] = NEG4;
        } else {
            // straddles the diagonal (one vec per row): per-component select
            float4 v = x4[i];
            float4 r;
            r.x = (c0 + 0 > row) ? NEGV : v.x;
            r.y = (c0 + 1 > row) ? NEGV : v.y;
            r.z = (c0 + 2 > row) ? NEGV : v.z;
            r.w = (c0 + 3 > row) ? NEGV : v.w;
            o4[i] = r;
        }
    }
}

extern "C" void kernel_launch(void* const* d_in, const int* in_sizes, int n_in,
                              void* d_out, int out_size, void* d_ws, size_t ws_size,
                              hipStream_t stream) {
    const float* x = (const float*)d_in[0];
    const int* n_ptr = (const int*)d_in[1];
    float* out = (float*)d_out;

    const int total = in_sizes[0];           // B * S * S = 134217728
    const int nvec = total >> 2;             // float4 count

    const int block = 256;
    const int grid = 8192;                   // grid-stride: ~16 iters/thread

    submask_kernel<<<grid, block, 0, stream>>>(
        (const float4*)x, (float4*)out, n_ptr, nvec);
}

// Round 3
// 140.421 us; speedup vs baseline: 1.3436x; 1.3436x over previous
//
#include <hip/hip_runtime.h>

#define NEGV -1000000000.0f

// Native vector type (HIP's float4 is a struct; nontemporal builtins
// require a scalar/native-vector pointee).
typedef float f32x4 __attribute__((ext_vector_type(4)));

// x: [B, S, S] fp32, S = 4096. mask = (row < n-1) && (col > row) -> NEGV.
// One 256-thread block per row. Per row, exactly nload float4s need a load
// (prefix up to the diagonal); the rest are pure NEG stores with NO load.
// nload is wave-uniform, so the load-skip is structural, not data-divergent.
__global__ __launch_bounds__(256) void submask_row_kernel(
    const f32x4* __restrict__ x4,
    f32x4* __restrict__ o4,
    const int* __restrict__ n_ptr)
{
    const int n = *n_ptr;                     // uniform scalar
    const int row = blockIdx.x & 4095;        // row within S x S matrix
    const bool full = (row >= n - 1);         // untouched row: plain copy
    const int nload = full ? 1024 : ((row >> 2) + 1);  // vecs needing a load
    const int sv    = full ? -1   : (row >> 2);        // straddle vec index
    const int rm    = row & 3;                // diagonal position within vec
    const size_t base = (size_t)blockIdx.x << 10;      // 1024 vecs per row
    const f32x4 NEG4 = {NEGV, NEGV, NEGV, NEGV};
    const int t = threadIdx.x;

#pragma unroll
    for (int k = 0; k < 4; ++k) {
        const int v = t + (k << 8);
        if (v < nload) {
            f32x4 d = __builtin_nontemporal_load(&x4[base + v]);
            if (v == sv) {
                // diagonal falls inside this vec: mask components past it
                if (rm < 1) d.y = NEGV;
                if (rm < 2) d.z = NEGV;
                if (rm < 3) d.w = NEGV;
            }
            __builtin_nontemporal_store(d, &o4[base + v]);
        } else {
            __builtin_nontemporal_store(NEG4, &o4[base + v]);
        }
    }
}

extern "C" void kernel_launch(void* const* d_in, const int* in_sizes, int n_in,
                              void* d_out, int out_size, void* d_ws, size_t ws_size,
                              hipStream_t stream) {
    const float* x = (const float*)d_in[0];
    const int* n_ptr = (const int*)d_in[1];
    float* out = (float*)d_out;

    const int total = in_sizes[0];            // B * S * S = 134217728
    const int rows = total >> 12;             // B * S = 32768 rows of 4096

    submask_row_kernel<<<rows, 256, 0, stream>>>(
        (const f32x4*)x, (f32x4*)out, n_ptr);
}